// Round 2
// baseline (442.196 us; speedup 1.0000x reference)
//
#include <hip/hip_runtime.h>

// PolyConv: h = sum_k theta[k] * L_sym^k x,  L_sym = I - D^{-1/2} A D^{-1/2}
// N=100000 nodes, E=1600000 edges, F=64 features, 5 theta terms.
//
// Round 16b: feature-chunked gather for per-XCD L2 residency. All bf16
// feature tables (xb, g0..g3) are stored CHUNK-MAJOR: 4 planes of 16
// features (32B per node per plane, 3.2MB per plane). Each gather pass
// runs 4 chunk phases in one launch (chunk-major block order); the active
// gather table per phase is one contiguous 3.2MB plane -> fits every
// XCD's 4MB L2 (vs 12.8MB full table, ~31% hit rate before). cblocks is
// a multiple of 8 so the same node slice maps to the same XCD across
// chunks (csr/rp re-reads become L2 hits). Non-temporal stores for gout/h
// keep the resident plane from being evicted by the output stream.
// (Fix vs r16: nontemporal builtins need native ext_vector_type, not
// HIP_vector_type uint4/float4.)

constexpr int kF = 64;
constexpr int CH = 4;                 // feature chunks
constexpr int CF = 16;                // features per chunk (32B bf16)
constexpr int BSHIFT = 8;             // bucket = dst >> 8  (256 nodes/bucket)
constexpr int NB = 1 << BSHIFT;       // 256 nodes per bucket
constexpr int TILE = 2048;            // edges per phase-A block (4/thread)
constexpr int KMAX = 512;             // array bound for K (=391)

typedef unsigned nv4u __attribute__((ext_vector_type(4)));   // nontemporal-safe
typedef float    nv4f __attribute__((ext_vector_type(4)));

static __device__ __forceinline__ float bfl(unsigned u) {        // low bf16 -> f32
    return __uint_as_float(u << 16);
}
static __device__ __forceinline__ float bfh(unsigned u) {        // high bf16 -> f32
    return __uint_as_float(u & 0xffff0000u);
}
static __device__ __forceinline__ unsigned f2bf(float f) {       // RNE f32 -> bf16
    unsigned u = __float_as_uint(f);
    return (u + 0x7fffu + ((u >> 16) & 1u)) >> 16;
}
static __device__ __forceinline__ unsigned pack2(float a, float b) {
    return f2bf(a) | (f2bf(b) << 16);
}

// Phase A: multisplit edges into K buckets (hist -> reserve -> direct global
// scatter with LDS cursors). dst/src register-cached across phases.
// Fused x (fp32) -> xb (bf16, CHUNK-MAJOR planes) conversion.
__global__ void k_binA(const int* __restrict__ src, const int* __restrict__ dst,
                       unsigned* __restrict__ pairs, int* __restrict__ gcursor,
                       const float4* __restrict__ x4, uint4* __restrict__ xb4,
                       int n8, int E, int K, int cap) {
    __shared__ int hist[KMAX];
    __shared__ int gb[KMAX];
    const int tid = threadIdx.x;        // blockDim = 512
    const long long tb = (long long)blockIdx.x * TILE;
    const int tcount = (int)min((long long)TILE, (long long)E - tb);
    const int Nn = n8 >> 3;             // nodes

    // fused x -> bf16 convert (disjoint slice per block), chunk-major out.
    // granule i = 8 floats = one (node, chunk, d) cell of 16B.
    {
        int per = (n8 + gridDim.x - 1) / (int)gridDim.x;
        int b0 = blockIdx.x * per;
        int b1 = min(b0 + per, n8);
        for (int i = b0 + tid; i < b1; i += 512) {
            float4 a = x4[2 * i];
            float4 b = x4[2 * i + 1];
            uint4 o;
            o.x = pack2(a.x, a.y);
            o.y = pack2(a.z, a.w);
            o.z = pack2(b.x, b.y);
            o.w = pack2(b.z, b.w);
            int nloc = i >> 3, sub = i & 7;
            int c = sub >> 1, dd = sub & 1;
            xb4[(size_t)c * ((size_t)Nn * 2) + (size_t)nloc * 2 + dd] = o;
        }
    }

    hist[tid] = 0;
    __syncthreads();
    int dc[4], sc[4];
    #pragma unroll
    for (int k = 0; k < 4; ++k) {
        int i = tid + k * 512;
        if (i < tcount) {
            dc[k] = dst[tb + i];
            sc[k] = src[tb + i];
            atomicAdd(&hist[dc[k] >> BSHIFT], 1);
        } else {
            dc[k] = -1;
        }
    }
    __syncthreads();
    int hv = hist[tid];
    gb[tid] = (tid < K && hv > 0) ? atomicAdd(&gcursor[tid], hv) : 0;
    hist[tid] = 0;                       // reuse as local cursor
    __syncthreads();
    #pragma unroll
    for (int k = 0; k < 4; ++k) {
        if (dc[k] >= 0) {
            int d = dc[k];
            int b = d >> BSHIFT;
            int pos = atomicAdd(&hist[b], 1);
            pairs[(size_t)b * cap + gb[b] + pos] =
                ((unsigned)(d & (NB - 1)) << 23) | (unsigned)sc[k];
        }
    }
}

// Phase B: one block (512 thr) per bucket of 256 nodes. In-kernel gbase
// scan, per-node counts -> LDS scan -> rp/dinv2/rdeg, scatter plain src ints
// to csr via absolute LDS cursors, then convert own bucket's xb->g0 slice
// (chunk-major planes) with LDS dinv.
__global__ void k_binB(const unsigned* __restrict__ pairs, const int* __restrict__ gcursor,
                       int* __restrict__ rp, float* __restrict__ dinv2,
                       float* __restrict__ rdeg, int* __restrict__ csr,
                       const uint4* __restrict__ xb4, uint4* __restrict__ g04,
                       int N, int E, int K, int cap) {
    __shared__ int gsc[KMAX];
    __shared__ int cnt[NB];
    __shared__ int stmp[NB];
    __shared__ int cur[NB];
    __shared__ float sdinv[NB];
    const int b = blockIdx.x;
    const int tid = threadIdx.x;        // blockDim = 512

    int gv = (tid < K) ? gcursor[tid] : 0;
    gsc[tid] = gv;
    __syncthreads();
    for (int o = 1; o < KMAX; o <<= 1) {
        int t = (tid >= o) ? gsc[tid - o] : 0;
        __syncthreads();
        gsc[tid] += t;
        __syncthreads();
    }
    const int ecnt = gcursor[b];
    const int base = gsc[b] - ecnt;     // inclusive - own = exclusive
    const unsigned* bp = pairs + (size_t)b * cap;

    if (tid < NB) cnt[tid] = 0;
    __syncthreads();
    for (int i = tid; i < ecnt; i += 512)
        atomicAdd(&cnt[bp[i] >> 23], 1);
    __syncthreads();
    int v = (tid < NB) ? cnt[tid] : 0;
    if (tid < NB) stmp[tid] = v;
    __syncthreads();
    for (int o = 1; o < NB; o <<= 1) {
        int t = (tid >= o && tid < NB) ? stmp[tid - o] : 0;
        __syncthreads();
        if (tid < NB) stmp[tid] += t;
        __syncthreads();
    }
    int node = (b << BSHIFT) + tid;
    if (tid < NB) {
        int abs0 = base + stmp[tid] - v;            // exclusive, absolute
        cur[tid] = abs0;
        float d = fmaxf((float)v, 1.0f);
        sdinv[tid] = rsqrtf(d);
        if (node < N) {
            rp[node] = abs0;
            dinv2[node] = 1.0f / d;
            rdeg[node]  = sqrtf(d);
        }
    }
    if (b == K - 1 && tid == 0) rp[N] = E;
    __syncthreads();
    for (int i = tid; i < ecnt; i += 512) {
        unsigned p = bp[i];
        int pos = atomicAdd(&cur[p >> 23], 1);      // absolute csr index
        csr[pos] = (int)(p & 0x7FFFFFu);
    }
    // fused g0 = bf16(dinv * x) for this bucket's nodes (chunk-major planes)
    const int nbase = b << BSHIFT;
    const int nn = min(NB, N - nbase);
    for (int c = 0; c < CH; ++c) {
        const uint4* xp = xb4 + (size_t)c * ((size_t)N * 2) + (size_t)nbase * 2;
        uint4*       gp = g04 + (size_t)c * ((size_t)N * 2) + (size_t)nbase * 2;
        for (int q = tid; q < nn * 2; q += 512) {
            float di = sdinv[q >> 1];
            uint4 xv = xp[q];
            uint4 o;
            o.x = pack2(di * bfl(xv.x), di * bfh(xv.x));
            o.y = pack2(di * bfl(xv.y), di * bfh(xv.y));
            o.z = pack2(di * bfl(xv.z), di * bfh(xv.z));
            o.w = pack2(di * bfl(xv.w), di * bfh(xv.w));
            gp[q] = o;
        }
    }
}

// Feature-chunked gather. Grid = CH * cblocks blocks; chunk-major block
// order serializes chunk phases so the active 3.2MB gin plane stays
// L2-resident per XCD. Per wave: 2 nodes (half=l>>5), 16 edges/iter
// (e=(l>>1)&15), 2 lanes per 32B row (d=l&1, uint4 each). Depth-2
// software pipeline on csr + row loads. fp32 accumulate, butterfly
// reduce over e bits (xor 2,4,8,16).
// !LAST: gout[plane] = bf16(gin - dinv2*acc)   (non-temporal store)
//  LAST: h[node, chunk*16 + d*8 ..] = t0*xb + rdeg*(t1*g1+t2*g2+t3*gin+t4*g4)
template <bool LAST>
__global__ void k_gather(const int* __restrict__ rp, const int* __restrict__ csr,
                         const unsigned short* __restrict__ gin,
                         const float* __restrict__ dinv2,
                         unsigned short* __restrict__ gout,
                         const unsigned short* __restrict__ xb,
                         const unsigned short* __restrict__ g1t,
                         const unsigned short* __restrict__ g2t,
                         const float* __restrict__ rdeg,
                         float* __restrict__ h, int n, int cblocks,
                         float t0, float t1, float t2, float t3, float t4) {
    const int chunk = blockIdx.x / cblocks;
    const int bidx  = blockIdx.x - chunk * cblocks;
    const int wid   = bidx * 4 + (threadIdx.x >> 6);
    const int lane  = threadIdx.x & 63;
    const int half  = lane >> 5;
    const int e     = (lane >> 1) & 15;
    const int d     = lane & 1;
    const int node  = wid * 2 + half;
    if (wid * 2 >= n) return;
    bool valid = node < n;
    int beg = valid ? rp[node] : 0;
    int end = valid ? rp[node + 1] : 0;
    int len = end - beg;
    int olen = __shfl_xor(len, 32, 64);
    int mlen = (len > olen) ? len : olen;   // pair max -> uniform trip count

    const unsigned short* gp = gin + (size_t)chunk * ((size_t)n * CF);

    float acc[8] = {0.f, 0.f, 0.f, 0.f, 0.f, 0.f, 0.f, 0.f};

    // pipeline state: current row (in flight), next csr index
    uint4 rc = make_uint4(0, 0, 0, 0);
    float wc = 0.f, wn = 0.f;
    int sn = 0;
    if (mlen > 0) {
        int j = beg + e;
        bool o = j < end;
        int s = csr[o ? j : 0];
        wc = o ? 1.f : 0.f;
        rc = *(const uint4*)(gp + (size_t)s * CF + (d << 3));
        int jb = beg + 16 + e;
        bool bnext = (16 < mlen) && (jb < end);
        sn = csr[bnext ? jb : 0];
        wn = bnext ? 1.f : 0.f;
    }
    for (int i = 0; i < mlen; i += 16) {
        // issue NEXT iteration's row (independent of rc wait)
        uint4 rn = *(const uint4*)(gp + (size_t)sn * CF + (d << 3));
        // prefetch csr two iterations ahead
        int jn = beg + i + 32 + e;
        bool tn = ((i + 32) < mlen) && (jn < end);
        int st = csr[tn ? jn : 0];
        float wt = tn ? 1.f : 0.f;
        // accumulate CURRENT row
        acc[0] += wc * bfl(rc.x); acc[1] += wc * bfh(rc.x);
        acc[2] += wc * bfl(rc.y); acc[3] += wc * bfh(rc.y);
        acc[4] += wc * bfl(rc.z); acc[5] += wc * bfh(rc.z);
        acc[6] += wc * bfl(rc.w); acc[7] += wc * bfh(rc.w);
        // rotate pipeline
        rc = rn; wc = wn;
        sn = st; wn = wt;
    }
    #pragma unroll
    for (int m = 2; m <= 16; m <<= 1) {
        #pragma unroll
        for (int i = 0; i < 8; ++i)
            acc[i] += __shfl_xor(acc[i], m, 64);
    }

    if (e == 0 && valid) {                   // lanes 0,1 and 32,33
        size_t off = (size_t)chunk * ((size_t)n * CF) + (size_t)node * CF + (d << 3);
        uint4 rr = *(const uint4*)(gin + off);
        float d2 = dinv2[node];
        float v[8];
        v[0] = bfl(rr.x) - d2 * acc[0]; v[1] = bfh(rr.x) - d2 * acc[1];
        v[2] = bfl(rr.y) - d2 * acc[2]; v[3] = bfh(rr.y) - d2 * acc[3];
        v[4] = bfl(rr.z) - d2 * acc[4]; v[5] = bfh(rr.z) - d2 * acc[5];
        v[6] = bfl(rr.w) - d2 * acc[6]; v[7] = bfh(rr.w) - d2 * acc[7];
        if (!LAST) {
            nv4u o;
            o.x = pack2(v[0], v[1]);
            o.y = pack2(v[2], v[3]);
            o.z = pack2(v[4], v[5]);
            o.w = pack2(v[6], v[7]);
            __builtin_nontemporal_store(o, (nv4u*)(gout + off));
        } else {
            nv4u xv = __builtin_nontemporal_load((const nv4u*)(xb + off));
            nv4u a  = __builtin_nontemporal_load((const nv4u*)(g1t + off));
            nv4u b  = __builtin_nontemporal_load((const nv4u*)(g2t + off));
            float rd = rdeg[node];
            float s1 = rd * t1, s2 = rd * t2, s3 = rd * t3, s4 = rd * t4;
            nv4f h0, h1;
            h0.x = t0 * bfl(xv.x) + s1 * bfl(a.x) + s2 * bfl(b.x) + s3 * bfl(rr.x) + s4 * v[0];
            h0.y = t0 * bfh(xv.x) + s1 * bfh(a.x) + s2 * bfh(b.x) + s3 * bfh(rr.x) + s4 * v[1];
            h0.z = t0 * bfl(xv.y) + s1 * bfl(a.y) + s2 * bfl(b.y) + s3 * bfl(rr.y) + s4 * v[2];
            h0.w = t0 * bfh(xv.y) + s1 * bfh(a.y) + s2 * bfh(b.y) + s3 * bfh(rr.y) + s4 * v[3];
            h1.x = t0 * bfl(xv.z) + s1 * bfl(a.z) + s2 * bfl(b.z) + s3 * bfl(rr.z) + s4 * v[4];
            h1.y = t0 * bfh(xv.z) + s1 * bfh(a.z) + s2 * bfh(b.z) + s3 * bfh(rr.z) + s4 * v[5];
            h1.z = t0 * bfl(xv.w) + s1 * bfl(a.w) + s2 * bfl(b.w) + s3 * bfl(rr.w) + s4 * v[6];
            h1.w = t0 * bfh(xv.w) + s1 * bfh(a.w) + s2 * bfh(b.w) + s3 * bfh(rr.w) + s4 * v[7];
            size_t hoff = (size_t)node * kF + chunk * CF + (d << 3);
            __builtin_nontemporal_store(h0, (nv4f*)(h + hoff));
            __builtin_nontemporal_store(h1, (nv4f*)(h + hoff + 4));
        }
    }
}

extern "C" void kernel_launch(void* const* d_in, const int* in_sizes, int n_in,
                              void* d_out, int out_size, void* d_ws, size_t ws_size,
                              hipStream_t stream) {
    const float* x  = (const float*)d_in[0];
    const int*   ei = (const int*)d_in[1];   // edge_index [2, E] row-major
    const int N = in_sizes[0] / kF;
    const int E = in_sizes[1] / 2;
    const int* src = ei;
    const int* dst = ei + E;
    float* h = (float*)d_out;

    const int K = (N + NB - 1) >> BSHIFT;         // 391 buckets (K <= KMAX)
    const int cap = 2 * ((E + K - 1) / K);        // per-bucket capacity

    // workspace (~73 MB): gcursor | rp | dinv2 | rdeg | csr | xb | g0..g3 |
    // pairs (aliases g3: g3 first written in pass 3, pairs dead after binB)
    char* ws = (char*)d_ws;
    size_t off = 0;
    auto carve = [&](size_t bytes) {
        void* p = ws + off;
        off = (off + bytes + 511) & ~(size_t)511;
        return p;
    };
    int*            gcursor = (int*)carve((size_t)K * 4);
    int*            rp      = (int*)carve((size_t)(N + 1) * 4);
    float*          dinv2   = (float*)carve((size_t)N * 4);
    float*          rdeg    = (float*)carve((size_t)N * 4);
    int*            csr     = (int*)carve((size_t)E * 4);
    unsigned short* xb      = (unsigned short*)carve((size_t)N * kF * 2);
    unsigned short* g0      = (unsigned short*)carve((size_t)N * kF * 2);
    unsigned short* g1      = (unsigned short*)carve((size_t)N * kF * 2);
    unsigned short* g2      = (unsigned short*)carve((size_t)N * kF * 2);
    size_t gbytes = (size_t)N * kF * 2;
    size_t pbytes = (size_t)K * cap * 4;
    unsigned short* g3      = (unsigned short*)carve(gbytes > pbytes ? gbytes : pbytes);
    unsigned*       pairs   = (unsigned*)g3;       // alias (see above)

    const float theta[5] = {0.6f, -0.4f, 0.3f, -0.2f, 0.1f};
    const int n8 = N * kF / 8;

    // ---- CSR build (multisplit) with fused x->bf16 convert and g0 ----
    hipMemsetAsync(gcursor, 0, (size_t)K * 4, stream);
    k_binA<<<(E + TILE - 1) / TILE, 512, 0, stream>>>(src, dst, pairs, gcursor,
                                                      (const float4*)x, (uint4*)xb,
                                                      n8, E, K, cap);
    k_binB<<<K, 512, 0, stream>>>(pairs, gcursor, rp, dinv2, rdeg, csr,
                                  (const uint4*)xb, (uint4*)g0, N, E, K, cap);

    // ---- 4 chunked gather passes; pass 4 fuses the h-combine epilogue ----
    const int nwaves = (N + 1) / 2;                // 2 nodes per wave
    int cblocks = (nwaves + 3) / 4;                // 4 waves per 256-thread block
    cblocks = (cblocks + 7) & ~7;                  // node-slice -> XCD stable across chunks
    const int gblocks = CH * cblocks;
    k_gather<false><<<gblocks, 256, 0, stream>>>(rp, csr, g0, dinv2, g1,
                                                 nullptr, nullptr, nullptr, nullptr,
                                                 nullptr, N, cblocks, 0, 0, 0, 0, 0);
    k_gather<false><<<gblocks, 256, 0, stream>>>(rp, csr, g1, dinv2, g2,
                                                 nullptr, nullptr, nullptr, nullptr,
                                                 nullptr, N, cblocks, 0, 0, 0, 0, 0);
    k_gather<false><<<gblocks, 256, 0, stream>>>(rp, csr, g2, dinv2, g3,
                                                 nullptr, nullptr, nullptr, nullptr,
                                                 nullptr, N, cblocks, 0, 0, 0, 0, 0);
    k_gather<true><<<gblocks, 256, 0, stream>>>(rp, csr, g3, dinv2, nullptr,
                                                xb, g1, g2, rdeg, h, N, cblocks,
                                                theta[0], theta[1], theta[2],
                                                theta[3], theta[4]);
}

// Round 3
// 244.519 us; speedup vs baseline: 1.8084x; 1.8084x over previous
//
#include <hip/hip_runtime.h>
#include <hip/hip_fp16.h>

// PolyConv: h = sum_k theta[k] * L_sym^k x,  L_sym = I - D^{-1/2} A D^{-1/2}
// N=100000 nodes, E=1600000 edges, F=64 features, 5 theta terms.
//
// Round 17: revert chunking (r16 was VALU-bound: 4x iterations). Flat
// 128B-row layout as r15, but feature tables are F16 (not bf16) and the
// gather inner loop accumulates PACKED with v_pk_add_f16 (1 op / 2 elems,
// no unpack): ~2.5x less VALU per gathered byte. Weight multiplies removed
// via zero-row trick: tables have row N == 0; OOB edge slots gather row N.
// binB zeroes g0's row N; each !LAST gather zeroes its gout row N; pairs
// aliases g1 (first written in gather pass 1, after pairs dies in binB).
// Nontemporal stores for gout/h + nontemporal loads for LAST streams keep
// the gather table L2-resident.

constexpr int kF = 64;
constexpr int BSHIFT = 8;             // bucket = dst >> 8  (256 nodes/bucket)
constexpr int NB = 1 << BSHIFT;       // 256 nodes per bucket
constexpr int TILE = 2048;            // edges per phase-A block (4/thread)
constexpr int KMAX = 512;             // array bound for K (=391)

typedef unsigned nv4u __attribute__((ext_vector_type(4)));   // nontemporal-safe
typedef float    nv4f __attribute__((ext_vector_type(4)));

static __device__ __forceinline__ float hlo(unsigned u) {        // low f16 -> f32
    return __half2float(__ushort_as_half((unsigned short)(u & 0xffffu)));
}
static __device__ __forceinline__ float hhi(unsigned u) {        // high f16 -> f32
    return __half2float(__ushort_as_half((unsigned short)(u >> 16)));
}
static __device__ __forceinline__ unsigned pack2h(float a, float b) { // RNE
    return (unsigned)__half_as_ushort(__float2half_rn(a)) |
           ((unsigned)__half_as_ushort(__float2half_rn(b)) << 16);
}
static __device__ __forceinline__ unsigned padd2(unsigned a, unsigned b) {
    __half2 ha = *reinterpret_cast<__half2*>(&a);
    __half2 hb = *reinterpret_cast<__half2*>(&b);
    __half2 hc = __hadd2(ha, hb);                 // v_pk_add_f16
    return *reinterpret_cast<unsigned*>(&hc);
}

// Phase A: multisplit edges into K buckets (hist -> reserve -> direct global
// scatter with LDS cursors). dst/src register-cached across phases.
// Fused x (fp32) -> xb (f16) conversion.
__global__ void k_binA(const int* __restrict__ src, const int* __restrict__ dst,
                       unsigned* __restrict__ pairs, int* __restrict__ gcursor,
                       const float4* __restrict__ x4, uint4* __restrict__ xb4,
                       int n8, int E, int K, int cap) {
    __shared__ int hist[KMAX];
    __shared__ int gb[KMAX];
    const int tid = threadIdx.x;        // blockDim = 512
    const long long tb = (long long)blockIdx.x * TILE;
    const int tcount = (int)min((long long)TILE, (long long)E - tb);

    // fused x -> f16 convert (disjoint slice per block)
    {
        int per = (n8 + gridDim.x - 1) / (int)gridDim.x;
        int b0 = blockIdx.x * per;
        int b1 = min(b0 + per, n8);
        for (int i = b0 + tid; i < b1; i += 512) {
            float4 a = x4[2 * i];
            float4 b = x4[2 * i + 1];
            uint4 o;
            o.x = pack2h(a.x, a.y);
            o.y = pack2h(a.z, a.w);
            o.z = pack2h(b.x, b.y);
            o.w = pack2h(b.z, b.w);
            xb4[i] = o;
        }
    }

    hist[tid] = 0;
    __syncthreads();
    int dc[4], sc[4];
    #pragma unroll
    for (int k = 0; k < 4; ++k) {
        int i = tid + k * 512;
        if (i < tcount) {
            dc[k] = dst[tb + i];
            sc[k] = src[tb + i];
            atomicAdd(&hist[dc[k] >> BSHIFT], 1);
        } else {
            dc[k] = -1;
        }
    }
    __syncthreads();
    int hv = hist[tid];
    gb[tid] = (tid < K && hv > 0) ? atomicAdd(&gcursor[tid], hv) : 0;
    hist[tid] = 0;                       // reuse as local cursor
    __syncthreads();
    #pragma unroll
    for (int k = 0; k < 4; ++k) {
        if (dc[k] >= 0) {
            int d = dc[k];
            int b = d >> BSHIFT;
            int pos = atomicAdd(&hist[b], 1);
            pairs[(size_t)b * cap + gb[b] + pos] =
                ((unsigned)(d & (NB - 1)) << 23) | (unsigned)sc[k];
        }
    }
}

// Phase B: one block (512 thr) per bucket of 256 nodes. In-kernel gbase
// scan, per-node counts -> LDS scan -> rp/dinv2/rdeg, scatter plain src ints
// to csr via absolute LDS cursors, then convert own bucket's xb->g0 slice
// with LDS dinv. Also zeroes g0's row N (zero-row for OOB gather slots).
__global__ void k_binB(const unsigned* __restrict__ pairs, const int* __restrict__ gcursor,
                       int* __restrict__ rp, float* __restrict__ dinv2,
                       float* __restrict__ rdeg, int* __restrict__ csr,
                       const uint4* __restrict__ xb, uint4* __restrict__ g0,
                       int N, int E, int K, int cap) {
    __shared__ int gsc[KMAX];
    __shared__ int cnt[NB];
    __shared__ int stmp[NB];
    __shared__ int cur[NB];
    __shared__ float sdinv[NB];
    const int b = blockIdx.x;
    const int tid = threadIdx.x;        // blockDim = 512

    if (b == 0 && tid < 8)               // zero row N of g0
        g0[((size_t)N << 3) + tid] = make_uint4(0, 0, 0, 0);

    int gv = (tid < K) ? gcursor[tid] : 0;
    gsc[tid] = gv;
    __syncthreads();
    for (int o = 1; o < KMAX; o <<= 1) {
        int t = (tid >= o) ? gsc[tid - o] : 0;
        __syncthreads();
        gsc[tid] += t;
        __syncthreads();
    }
    const int ecnt = gcursor[b];
    const int base = gsc[b] - ecnt;     // inclusive - own = exclusive
    const unsigned* bp = pairs + (size_t)b * cap;

    if (tid < NB) cnt[tid] = 0;
    __syncthreads();
    for (int i = tid; i < ecnt; i += 512)
        atomicAdd(&cnt[bp[i] >> 23], 1);
    __syncthreads();
    int v = (tid < NB) ? cnt[tid] : 0;
    if (tid < NB) stmp[tid] = v;
    __syncthreads();
    for (int o = 1; o < NB; o <<= 1) {
        int t = (tid >= o && tid < NB) ? stmp[tid - o] : 0;
        __syncthreads();
        if (tid < NB) stmp[tid] += t;
        __syncthreads();
    }
    int node = (b << BSHIFT) + tid;
    if (tid < NB) {
        int abs0 = base + stmp[tid] - v;            // exclusive, absolute
        cur[tid] = abs0;
        float d = fmaxf((float)v, 1.0f);
        sdinv[tid] = rsqrtf(d);
        if (node < N) {
            rp[node] = abs0;
            dinv2[node] = 1.0f / d;
            rdeg[node]  = sqrtf(d);
        }
    }
    if (b == K - 1 && tid == 0) rp[N] = E;
    __syncthreads();
    for (int i = tid; i < ecnt; i += 512) {
        unsigned p = bp[i];
        int pos = atomicAdd(&cur[p >> 23], 1);      // absolute csr index
        csr[pos] = (int)(p & 0x7FFFFFu);
    }
    // fused g0 = f16(dinv * x) for this bucket's nodes (streaming 32KB)
    const int nbase = b << BSHIFT;
    const int qmax = min(NB, N - nbase) << 3;       // 8 uint4 per node
    const uint4* xbp = xb + ((size_t)nbase << 3);
    uint4* g0p = g0 + ((size_t)nbase << 3);
    for (int q = tid; q < qmax; q += 512) {
        float di = sdinv[q >> 3];
        uint4 xv = xbp[q];
        uint4 o;
        o.x = pack2h(di * hlo(xv.x), di * hhi(xv.x));
        o.y = pack2h(di * hlo(xv.y), di * hhi(xv.y));
        o.z = pack2h(di * hlo(xv.z), di * hhi(xv.z));
        o.w = pack2h(di * hlo(xv.w), di * hhi(xv.w));
        g0p[q] = o;
    }
}

// TWO nodes per wave, f16 feature tables (128B rows), depth-2 software
// pipeline (csr one iter ahead, rows issued before accumulate). Lane l:
// half = l>>5, r = (l>>3)&3, c = l&7. Packed v_pk_add_f16 accumulate;
// OOB slots gather the zero row at index n (no weight selects).
// Butterfly ^8,^16 -> lanes {0..7,32..39}.
// !LAST epilogue: gout[d] = f16(gin[d] - dinv2[d]*acc)  (+ zero row N)
//  LAST epilogue: h[d] = t0*xb[d] + rdeg[d]*(t1*g1+t2*g2+t3*gin+t4*g4),
//                 g4 = gin[d] - dinv2[d]*acc computed in-register.
template <bool LAST>
__global__ void k_gather(const int* __restrict__ rp, const int* __restrict__ csr,
                         const unsigned short* __restrict__ gin,
                         const float* __restrict__ dinv2,
                         unsigned short* __restrict__ gout,
                         const unsigned short* __restrict__ xb,
                         const unsigned short* __restrict__ g1t,
                         const unsigned short* __restrict__ g2t,
                         const float* __restrict__ rdeg,
                         float* __restrict__ h, int n,
                         float t0, float t1, float t2, float t3, float t4) {
    if (!LAST && blockIdx.x == 0 && threadIdx.x < 8)   // zero row N of gout
        *(((uint4*)(gout + ((size_t)n << 6))) + threadIdx.x) = make_uint4(0, 0, 0, 0);

    int wid = (blockIdx.x * blockDim.x + threadIdx.x) >> 6;
    int lane = threadIdx.x & 63;
    int half = lane >> 5;
    int r = (lane >> 3) & 3;
    int c = lane & 7;
    int node = wid * 2 + half;
    if (wid * 2 >= n) return;
    bool valid = node < n;
    int beg = valid ? rp[node] : 0;
    int end = valid ? rp[node + 1] : 0;
    int len = end - beg;
    int olen = __shfl_xor(len, 32, 64);
    int mlen = (len > olen) ? len : olen;   // pair max -> uniform trip count

    unsigned acc[4] = {0u, 0u, 0u, 0u};     // packed f16 pairs

    // pipeline state: current rows (in flight), next row indices
    uint4 rc1 = make_uint4(0, 0, 0, 0), rc2 = make_uint4(0, 0, 0, 0);
    int sn1 = n, sn2 = n;
    if (mlen > 0) {
        int j1 = beg + r, j2 = j1 + 4;
        bool o1 = j1 < end, o2 = j2 < end;
        int s1 = csr[o1 ? j1 : 0]; s1 = o1 ? s1 : n;
        int s2 = csr[o2 ? j2 : 0]; s2 = o2 ? s2 : n;
        rc1 = *(const uint4*)(gin + ((size_t)s1 << 6) + (c << 3));
        rc2 = *(const uint4*)(gin + ((size_t)s2 << 6) + (c << 3));
        int j1b = beg + 8 + r, j2b = j1b + 4;
        bool vb = 8 < mlen;
        bool b1 = vb && (j1b < end), b2 = vb && (j2b < end);
        sn1 = csr[b1 ? j1b : 0]; sn1 = b1 ? sn1 : n;
        sn2 = csr[b2 ? j2b : 0]; sn2 = b2 ? sn2 : n;
    }
    for (int i = 0; i < mlen; i += 8) {
        // issue NEXT iteration's rows (independent of rc1/rc2 wait)
        uint4 rn1 = *(const uint4*)(gin + ((size_t)sn1 << 6) + (c << 3));
        uint4 rn2 = *(const uint4*)(gin + ((size_t)sn2 << 6) + (c << 3));
        // prefetch csr two iterations ahead
        int j1n = beg + i + 16 + r, j2n = j1n + 4;
        bool vn = (i + 16) < mlen;
        bool t1c = vn && (j1n < end), t2c = vn && (j2n < end);
        int st1 = csr[t1c ? j1n : 0]; st1 = t1c ? st1 : n;
        int st2 = csr[t2c ? j2n : 0]; st2 = t2c ? st2 : n;
        // accumulate CURRENT rows (packed f16)
        acc[0] = padd2(acc[0], rc1.x); acc[1] = padd2(acc[1], rc1.y);
        acc[2] = padd2(acc[2], rc1.z); acc[3] = padd2(acc[3], rc1.w);
        acc[0] = padd2(acc[0], rc2.x); acc[1] = padd2(acc[1], rc2.y);
        acc[2] = padd2(acc[2], rc2.z); acc[3] = padd2(acc[3], rc2.w);
        // rotate pipeline
        rc1 = rn1; rc2 = rn2;
        sn1 = st1; sn2 = st2;
    }
    #pragma unroll
    for (int m = 8; m <= 16; m <<= 1) {
        #pragma unroll
        for (int i = 0; i < 4; ++i)
            acc[i] = padd2(acc[i], __shfl_xor(acc[i], m, 64));
    }

    if (r == 0 && valid) {                   // lanes 0..7 and 32..39
        size_t off = ((size_t)node << 6) + (c << 3);
        uint4 rr = *(const uint4*)(gin + off);
        float d2 = dinv2[node];
        float v[8];
        v[0] = hlo(rr.x) - d2 * hlo(acc[0]); v[1] = hhi(rr.x) - d2 * hhi(acc[0]);
        v[2] = hlo(rr.y) - d2 * hlo(acc[1]); v[3] = hhi(rr.y) - d2 * hhi(acc[1]);
        v[4] = hlo(rr.z) - d2 * hlo(acc[2]); v[5] = hhi(rr.z) - d2 * hhi(acc[2]);
        v[6] = hlo(rr.w) - d2 * hlo(acc[3]); v[7] = hhi(rr.w) - d2 * hhi(acc[3]);
        if (!LAST) {
            nv4u o;
            o.x = pack2h(v[0], v[1]);
            o.y = pack2h(v[2], v[3]);
            o.z = pack2h(v[4], v[5]);
            o.w = pack2h(v[6], v[7]);
            __builtin_nontemporal_store(o, (nv4u*)(gout + off));
        } else {
            nv4u xv = __builtin_nontemporal_load((const nv4u*)(xb + off));
            nv4u a  = __builtin_nontemporal_load((const nv4u*)(g1t + off));
            nv4u b  = __builtin_nontemporal_load((const nv4u*)(g2t + off));
            float rd = rdeg[node];
            float s1 = rd * t1, s2 = rd * t2, s3 = rd * t3, s4 = rd * t4;
            nv4f h0, h1;
            h0.x = t0 * hlo(xv.x) + s1 * hlo(a.x) + s2 * hlo(b.x) + s3 * hlo(rr.x) + s4 * v[0];
            h0.y = t0 * hhi(xv.x) + s1 * hhi(a.x) + s2 * hhi(b.x) + s3 * hhi(rr.x) + s4 * v[1];
            h0.z = t0 * hlo(xv.y) + s1 * hlo(a.y) + s2 * hlo(b.y) + s3 * hlo(rr.y) + s4 * v[2];
            h0.w = t0 * hhi(xv.y) + s1 * hhi(a.y) + s2 * hhi(b.y) + s3 * hhi(rr.y) + s4 * v[3];
            h1.x = t0 * hlo(xv.z) + s1 * hlo(a.z) + s2 * hlo(b.z) + s3 * hlo(rr.z) + s4 * v[4];
            h1.y = t0 * hhi(xv.z) + s1 * hhi(a.z) + s2 * hhi(b.z) + s3 * hhi(rr.z) + s4 * v[5];
            h1.z = t0 * hlo(xv.w) + s1 * hlo(a.w) + s2 * hlo(b.w) + s3 * hlo(rr.w) + s4 * v[6];
            h1.w = t0 * hhi(xv.w) + s1 * hhi(a.w) + s2 * hhi(b.w) + s3 * hhi(rr.w) + s4 * v[7];
            __builtin_nontemporal_store(h0, (nv4f*)(h + off));
            __builtin_nontemporal_store(h1, (nv4f*)(h + off + 4));
        }
    }
}

extern "C" void kernel_launch(void* const* d_in, const int* in_sizes, int n_in,
                              void* d_out, int out_size, void* d_ws, size_t ws_size,
                              hipStream_t stream) {
    const float* x  = (const float*)d_in[0];
    const int*   ei = (const int*)d_in[1];   // edge_index [2, E] row-major
    const int N = in_sizes[0] / kF;
    const int E = in_sizes[1] / 2;
    const int* src = ei;
    const int* dst = ei + E;
    float* h = (float*)d_out;

    const int K = (N + NB - 1) >> BSHIFT;         // 391 buckets (K <= KMAX)
    const int cap = 2 * ((E + K - 1) / K);        // per-bucket capacity

    // workspace (~72 MB): gcursor | rp | dinv2 | rdeg | csr | xb | g0 |
    // g1 (aliases pairs: g1 first written in gather pass 1; pairs dead
    // after binB) | g2 | g3.  g0..g3 have N+1 rows (row N = zeros).
    char* ws = (char*)d_ws;
    size_t off = 0;
    auto carve = [&](size_t bytes) {
        void* p = ws + off;
        off = (off + bytes + 511) & ~(size_t)511;
        return p;
    };
    size_t gbytes = (size_t)(N + 1) * kF * 2;
    int*            gcursor = (int*)carve((size_t)K * 4);
    int*            rp      = (int*)carve((size_t)(N + 1) * 4);
    float*          dinv2   = (float*)carve((size_t)N * 4);
    float*          rdeg    = (float*)carve((size_t)N * 4);
    int*            csr     = (int*)carve((size_t)E * 4);
    unsigned short* xb      = (unsigned short*)carve((size_t)N * kF * 2);
    unsigned short* g0      = (unsigned short*)carve(gbytes);
    size_t pbytes = (size_t)K * cap * 4;
    unsigned short* g1      = (unsigned short*)carve(gbytes > pbytes ? gbytes : pbytes);
    unsigned short* g2      = (unsigned short*)carve(gbytes);
    unsigned short* g3      = (unsigned short*)carve(gbytes);
    unsigned*       pairs   = (unsigned*)g1;       // alias (see above)

    const float theta[5] = {0.6f, -0.4f, 0.3f, -0.2f, 0.1f};
    const int n8 = N * kF / 8;

    // ---- CSR build (multisplit) with fused x->f16 convert and g0 ----
    hipMemsetAsync(gcursor, 0, (size_t)K * 4, stream);
    k_binA<<<(E + TILE - 1) / TILE, 512, 0, stream>>>(src, dst, pairs, gcursor,
                                                      (const float4*)x, (uint4*)xb,
                                                      n8, E, K, cap);
    k_binB<<<K, 512, 0, stream>>>(pairs, gcursor, rp, dinv2, rdeg, csr,
                                  (const uint4*)xb, (uint4*)g0, N, E, K, cap);

    // ---- 4 gather passes; pass 4 fuses the h-combine epilogue ----
    const int nwaves = (N + 1) / 2;                // 2 nodes per wave
    const int gblocks = (nwaves + 3) / 4;          // 4 waves per 256-thread block
    k_gather<false><<<gblocks, 256, 0, stream>>>(rp, csr, g0, dinv2, g1,
                                                 nullptr, nullptr, nullptr, nullptr,
                                                 nullptr, N, 0, 0, 0, 0, 0);
    k_gather<false><<<gblocks, 256, 0, stream>>>(rp, csr, g1, dinv2, g2,
                                                 nullptr, nullptr, nullptr, nullptr,
                                                 nullptr, N, 0, 0, 0, 0, 0);
    k_gather<false><<<gblocks, 256, 0, stream>>>(rp, csr, g2, dinv2, g3,
                                                 nullptr, nullptr, nullptr, nullptr,
                                                 nullptr, N, 0, 0, 0, 0, 0);
    k_gather<true><<<gblocks, 256, 0, stream>>>(rp, csr, g3, dinv2, nullptr,
                                                xb, g1, g2, rdeg, h, N,
                                                theta[0], theta[1], theta[2],
                                                theta[3], theta[4]);
}